// Round 7
// baseline (900.085 us; speedup 1.0000x reference)
//
#include <hip/hip_runtime.h>
#include <math.h>

#define HH 1024
#define AA 180
#define BB 16
#define NCOL (BB*AA)          // 2880 (b,angle) columns
#define RSP 1028              // pair-row stride (float2 entries)
#define GUARD 48              // fallback path: zero guard floats each side
#define RS 1120               // fallback row stride
#define PI_D 3.14159265358979323846

#define GANG 45               // angles staged per group (180 = 4*45)
#define WIN 48                // window entries (float2) per angle

// ws float-offsets
#define OFF_CG   0            // 512 filter coeffs
#define OFF_CST  512          // float4[180]: (512c, 512s, D8=-8*DEL*512*s, 0)
#define OFF_CST2 1232         // float2[180]: (c,s) fallback table
#define OFF_DATA 1600         // pair rows (float2[NCOL*RSP]) or fallback xaf

__device__ __forceinline__ float fractf_(float x) {
#if __has_builtin(__builtin_amdgcn_fractf)
    return __builtin_amdgcn_fractf(x);   // v_fract_f32
#else
    return x - floorf(x);
#endif
}

// ---------------- tables ----------------
__global__ __launch_bounds__(512) void k_tables(float* __restrict__ ws) {
    int t = threadIdx.x;
    if (t < 512) {
        double d = 2.0 * t + 1.0;
        ws[OFF_CG + t] = (float)(-2.0 / (PI_D * PI_D * d * d));
    }
    if (t < AA) {
        float thf = (float)t * 0.017453292519943295f;  // fp32(pi/180)
        double th = (double)thf;
        double c = cos(th), s = sin(th);
        float4* cst4 = (float4*)(ws + OFF_CST);
        // D8 = d(iy)/d(k) for y-step of 8 pixels: -8*DEL*512*s = -(8192/1023)*s
        cst4[t] = make_float4((float)(512.0 * c), (float)(512.0 * s),
                              (float)(-(8192.0 / 1023.0) * s), 0.f);
        float2* cst2 = (float2*)(ws + OFF_CST2);
        cst2[t] = make_float2((float)(512.0 * c), (float)(512.0 * s));
    }
}

// ---------------- shared conv core (fused angle-interp + ramp filter) ----------------
__device__ __forceinline__ void filter_core(const float* __restrict__ x,
                                            const float* __restrict__ cg,
                                            float* xsp, int t, int col,
                                            float acc[16]) {
    int b = col / AA, a = col - b * AA;

    float4* z4 = (float4*)xsp;
    #pragma unroll
    for (int i = t; i < 816; i += 64) z4[i] = make_float4(0.f, 0.f, 0.f, 0.f);
    __syncthreads();

    float ixf = (float)a * (float)(180.0/179.0) - 0.5f;
    float fl = floorf(ixf);
    int i0 = (int)fl;
    float fx = ixf - fl;
    float w0 = (i0 >= 0)      ? (1.0f - fx) : 0.0f;
    float w1 = (i0 + 1 < AA)  ? fx          : 0.0f;
    int c0 = max(i0, 0);
    int c1 = min(i0 + 1, AA - 1);
    const float* xb = x + (size_t)b * HH * AA;
    for (int i = t; i < HH; i += 64) {
        float v = w0 * xb[i * AA + c0] + w1 * xb[i * AA + c1];
        int q = 1024 + i;
        xsp[q + (q >> 4)] = v;         // lane stride 17 -> conflict-free
    }
    __syncthreads();

    int pp = 17 * t;
    float Lw[16], Rw[16];
    #pragma unroll
    for (int m = 0; m < 16; ++m) {
        int f = 1024 + m;
        acc[m] = 0.5f * xsp[pp + f + (f >> 4)];
    }
    #pragma unroll
    for (int m = 0; m < 16; ++m) {
        int f = 1 + m;
        Lw[(m + 1) & 15] = xsp[pp + f + (f >> 4)];
        int g = 2047 + m;
        Rw[(m - 1) & 15] = xsp[pp + g + (g >> 4)];
    }

    for (int it0 = 0; it0 < 512; it0 += 8) {
        #pragma unroll
        for (int u = 0; u < 8; ++u) {
            int it = it0 + u;
            float cv = cg[511 - it];
            #pragma unroll
            for (int m = 0; m < 16; ++m) {
                acc[m] = fmaf(cv, Lw[(m + 2*u + 1) & 15] + Rw[(m - 2*u - 1) & 15], acc[m]);
            }
            int fL  = 2*it + 17;
            Lw[(2*u + 1) & 15] = xsp[pp + fL  + (fL  >> 4)];
            int fL2 = 2*it + 18;
            Lw[(2*u + 2) & 15] = xsp[pp + fL2 + (fL2 >> 4)];
            int fR  = 2045 - 2*it;
            Rw[(13 - 2*u) & 15] = xsp[pp + fR  + (fR  >> 4)];
            int fR2 = 2046 - 2*it;
            Rw[(14 - 2*u) & 15] = xsp[pp + fR2 + (fR2 >> 4)];
        }
    }
}

// ---------------- pair-output filter (SLOPE layout) ----------------
// pair[s] = (y[s-2], y[s-1]-y[s-2]) * SC, zero outside; valid s in [0,1026].
__global__ __launch_bounds__(64) void k_filter_pair(const float* __restrict__ x,
                                                    const float* __restrict__ cg,
                                                    float2* __restrict__ pair) {
    __shared__ float xsp[3264];
    int t = threadIdx.x;
    int col = blockIdx.x;
    float acc[16];
    filter_core(x, cg, xsp, t, col, acc);

    const float SC = (float)(PI_D / 360.0);
    float yv[16];
    #pragma unroll
    for (int m = 0; m < 16; ++m) yv[m] = acc[m] * SC;
    float ynext = __shfl_down(yv[0], 1);
    if (t == 63) ynext = 0.f;

    float2* rowp = pair + (size_t)col * RSP;
    int s0 = 16 * t + 2;
    #pragma unroll
    for (int m = 0; m < 15; ++m) rowp[s0 + m] = make_float2(yv[m], yv[m + 1] - yv[m]);
    rowp[s0 + 15] = make_float2(yv[15], ynext - yv[15]);
    if (t == 0) {
        rowp[0] = make_float2(0.f, 0.f);
        rowp[1] = make_float2(0.f, yv[0]);     // (v=0, dv=y0-0)
    }
    if (t == 63) rowp[1026] = make_float2(0.f, 0.f);
}

// ---------------- paired backprojection group compute ----------------
// Thread owns a 2x2 footprint: x-pair (x0,x0+1) at rows (ybase+16h, +8).
// R6 BUGFIX: the P chain uses uy at the BASE row ybase=y0+ty8 (exactly R1's
// thread ty=ty8), with the 16h-row displacement applied ONLY via hF*D8 —
// R6 had computed uy at the actual row AND added hF*D8 (double-counted).
// With base-row uy, PA/PB/PC/PD are bit-for-bit R1's P_{2h}, P_{2h+1}.
// Gather: dP between x-adjacent pixels = (1024/1023)cos in (-1.001,1.001] ->
// indices differ by <=1 except |cos|>0.999 AND fract>=0.999 (|dj|=2, rare).
// Fast path: ONE ds_read2_b64 [jmin,jmin+1] per row-pair serves both x;
// cndmask select. Rare |dj|=2 fixed by wave-voted corrective gather.
template<bool CLAMP>
__device__ __forceinline__ void bp_group2(const float4* angf4_s,
                                          const float2* win,
                                          float ux0, float ux1, float nuy, float hF,
                                          float& a00, float& a01,
                                          float& a10, float& a11)
{
    #pragma unroll 5
    for (int g = 0; g < GANG; ++g) {
        float4 cb = angf4_s[g];             // uniform-address b128 broadcast (cheap)
        float t0  = fmaf(nuy, cb.y, cb.w);
        float Pb0 = fmaf(ux0, cb.x, t0);    // R1's P0 for x0 (base row)
        float Pb1 = fmaf(ux1, cb.x, t0);    // R1's P0 for x1
        float PA  = fmaf(hF, cb.z, Pb0);    // R1's P_{2h} (x0): fmaf(0,..)=id, fmaf(2,..)=P2
        float PB  = fmaf(hF, cb.z, Pb1);    // R1's P_{2h} (x1)
        float PC  = PA + cb.z;              // R1's P_{2h+1} (x0)
        float PD  = PB + cb.z;              // R1's P_{2h+1} (x1)
        int jA = (int)PA, jB = (int)PB, jC = (int)PC, jD = (int)PD;
        if (CLAMP) {
            jA = min(max(jA, 0), WIN - 1); jB = min(max(jB, 0), WIN - 1);
            jC = min(max(jC, 0), WIN - 1); jD = min(max(jD, 0), WIN - 1);
        }
        const float2* wg = win + g * WIN;
        int jmAB = min(jA, jB);
        int jmCD = min(jC, jD);
        const float2* wpAB = wg + jmAB;     // adjacent loads -> ds_read2_b64
        float2 q0 = wpAB[0];
        float2 q1 = wpAB[1];
        const float2* wpCD = wg + jmCD;
        float2 r0 = wpCD[0];
        float2 r1 = wpCD[1];
        int eA = jA - jmAB, eB = jB - jmAB;
        int eC = jC - jmCD, eD = jD - jmCD;
        float dAv = (eA == 0) ? q0.x : q1.x, dAd = (eA == 0) ? q0.y : q1.y;
        float dBv = (eB == 0) ? q0.x : q1.x, dBd = (eB == 0) ? q0.y : q1.y;
        float dCv = (eC == 0) ? r0.x : r1.x, dCd = (eC == 0) ? r0.y : r1.y;
        float dDv = (eD == 0) ? r0.x : r1.x, dDd = (eD == 0) ? r0.y : r1.y;
        if (__any((eA | eB | eC | eD) & 2)) {   // rare |dj|=2 corrective path
            float2 xA = wg[jA]; dAv = (eA & 2) ? xA.x : dAv; dAd = (eA & 2) ? xA.y : dAd;
            float2 xB = wg[jB]; dBv = (eB & 2) ? xB.x : dBv; dBd = (eB & 2) ? xB.y : dBd;
            float2 xC = wg[jC]; dCv = (eC & 2) ? xC.x : dCv; dCd = (eC & 2) ? xC.y : dCd;
            float2 xD = wg[jD]; dDv = (eD & 2) ? xD.x : dDv; dDd = (eD & 2) ? xD.y : dDd;
        }
        float fA = fractf_(PA), fB = fractf_(PB), fC = fractf_(PC), fD = fractf_(PD);
        a00 = fmaf(fA, dAd, a00 + dAv);
        a01 = fmaf(fB, dBd, a01 + dBv);
        a10 = fmaf(fC, dCd, a10 + dCv);
        a11 = fmaf(fD, dDd, a11 + dDv);
    }
}

// ---------------- LDS-staged backprojection (R7 = R6 + base-row fix) ----------------
__global__ __launch_bounds__(256, 4) void k_bproj_lds(const float* __restrict__ ws,
                                                      const float2* __restrict__ pair,
                                                      float* __restrict__ out) {
    __shared__ float4 winbuf[GANG * (WIN/2)];   // 17280 B
    __shared__ float4 angf4[GANG];              // (512c, 512s, D8, bf)
    __shared__ int    baseL[GANG];

    const float4* cst = (const float4*)(ws + OFF_CST);
    int t = threadIdx.x;
    int n = blockIdx.x;
    // XCD-batch swizzle: blocks ≡ i (mod 8) handle batches {i, i+8} -> per-XCD
    // pair working set ~3 MB -> L2-resident.
    int b    = (n & 7) + 8 * ((n >> 3) & 1);
    int tile = n >> 4;                  // [0,1024)
    int bx = tile & 31;                 // x-tile (32 px)
    int by = tile >> 5;                 // y-tile (32 px)
    int txp = t & 15;                   // x-pair index [0,16)
    int ty8 = (t >> 4) & 7;             // [0,8)
    int h   = t >> 7;                   // {0,1}: k-slot pair {0,1} or {2,3}
    int xg0 = bx * 32 + 2 * txp;
    int xg1 = xg0 + 1;
    int y0 = by * 32;
    int ybase = y0 + ty8;               // P-chain base row (R1's ty)
    int yg = ybase + 16 * h;            // actual store row; thread also owns yg+8
    float hF = h ? 2.0f : 0.0f;

    const float DEL = (float)(2.0 / 1023.0);
    // bit-exact jnp.linspace replication (mul then add, no contraction)
    float ux0 = __fadd_rn(__fmul_rn((float)xg0,   DEL), -1.0f);
    float ux1 = __fadd_rn(__fmul_rn((float)xg1,   DEL), -1.0f);
    float uyB = __fadd_rn(__fmul_rn((float)ybase, DEL), -1.0f);  // BASE row uy
    float nuy = -uyB;

    // tile-uniform corner coords
    float cxl = __fadd_rn(__fmul_rn((float)(bx*32),      DEL), -1.0f);
    float cxh = __fadd_rn(__fmul_rn((float)(bx*32 + 31), DEL), -1.0f);
    float cyl = __fadd_rn(__fmul_rn((float)(y0),         DEL), -1.0f);
    float cyh = __fadd_rn(__fmul_rn((float)(y0 + 31),    DEL), -1.0f);

    float minax = (cxl <= 0.f && cxh >= 0.f) ? 0.f : fminf(fabsf(cxl), fabsf(cxh));
    float minay = (cyl <= 0.f && cyh >= 0.f) ? 0.f : fminf(fabsf(cyl), fabsf(cyh));
    float rmin2 = minax * minax + minay * minay;
    float maxax = fmaxf(fabsf(cxl), fabsf(cxh));
    float maxay = fmaxf(fabsf(cyl), fabsf(cyh));
    float rmax2 = maxax * maxax + maxay * maxay;

    size_t o0 = ((size_t)b << 20) + ((size_t)yg << 10) + (size_t)xg0;
    float* p0 = out + o0;               // rows yg and yg+8, 2 floats each

    if (rmin2 > 1.000001f) {            // tile fully outside: zeros, no barriers hit
        *(float2*)(p0)             = make_float2(0.f, 0.f);
        *(float2*)(p0 + (8 << 10)) = make_float2(0.f, 0.f);
        return;                          // block-uniform: no divergent-barrier hazard
    }

    bool interior = (rmax2 <= 0.9999f);
    const float2* slab = pair + (size_t)b * (AA * RSP);
    const float2* win = (const float2*)winbuf;
    float a00 = 0.f, a01 = 0.f, a10 = 0.f, a11 = 0.f;
    float nyl = -cyl, nyh = -cyh;

    for (int g0 = 0; g0 < AA; g0 += GANG) {
        // --- per-angle window bases + constants (tile-uniform) ---
        if (t < GANG) {
            float4 cs = cst[g0 + t];    // vector load (t varies)
            float mpx = fminf(cxl * cs.x, cxh * cs.x);
            float mpy = fminf(nyl * cs.y, nyh * cs.y);
            float minP = mpx + mpy + 513.5f;
            int base = (int)floorf(minP) - 1;
            base = min(max(base, 0), 1027 - WIN);
            base &= ~1;                 // 16B-align window for float4 staging
            baseL[t] = base;
            angf4[t] = make_float4(cs.x, cs.y, cs.z, 513.5f - (float)base);
        }
        __syncthreads();

        // --- coalesced staging: 45 angles x 24 float4 (48 float2) ---
        for (int idx = t; idx < GANG * (WIN/2); idx += 256) {
            int al = idx / (WIN/2);
            int w  = idx - (WIN/2) * al;
            const float4* rp4 = (const float4*)(slab + (size_t)(g0 + al) * RSP + baseL[al]);
            winbuf[idx] = rp4[w];
        }
        __syncthreads();

        if (interior) bp_group2<false>(angf4, win, ux0, ux1, nuy, hF, a00, a01, a10, a11);
        else          bp_group2<true >(angf4, win, ux0, ux1, nuy, hF, a00, a01, a10, a11);
        __syncthreads();   // protect baseL/angf4/win before next group
    }

    if (interior) {
        *(float2*)(p0)             = make_float2(a00, a01);
        *(float2*)(p0 + (8 << 10)) = make_float2(a10, a11);
    } else {
        // bit-exact circle mask per pixel at the ACTUAL rows (yg, yg+8)
        float uyA = __fadd_rn(__fmul_rn((float)yg,       DEL), -1.0f);
        float uyC = __fadd_rn(__fmul_rn((float)(yg + 8), DEL), -1.0f);
        float xx0 = __fmul_rn(ux0, ux0);
        float xx1 = __fmul_rn(ux1, ux1);
        float r2A = __fadd_rn(xx0, __fmul_rn(uyA, uyA));
        float r2B = __fadd_rn(xx1, __fmul_rn(uyA, uyA));
        float r2C = __fadd_rn(xx0, __fmul_rn(uyC, uyC));
        float r2D = __fadd_rn(xx1, __fmul_rn(uyC, uyC));
        *(float2*)(p0)             = make_float2((r2A <= 1.0f) ? a00 : 0.f,
                                                 (r2B <= 1.0f) ? a01 : 0.f);
        *(float2*)(p0 + (8 << 10)) = make_float2((r2C <= 1.0f) ? a10 : 0.f,
                                                 (r2D <= 1.0f) ? a11 : 0.f);
    }
}

// ================= fallback path (R3, proven) — used if ws too small ==========
__global__ __launch_bounds__(64) void k_filter_sc(const float* __restrict__ x,
                                                  const float* __restrict__ cg,
                                                  float* __restrict__ xaf) {
    __shared__ float xsp[3264];
    int t = threadIdx.x;
    int col = blockIdx.x;
    float acc[16];
    filter_core(x, cg, xsp, t, col, acc);

    const float SC = (float)(PI_D / 360.0);
    float* rb = xaf + (size_t)col * RS;
    if (t < 12)            ((float4*)rb)[t]              = make_float4(0.f,0.f,0.f,0.f);
    else if (t < 24)       ((float4*)rb)[268 + (t - 12)] = make_float4(0.f,0.f,0.f,0.f);
    float4* o4 = (float4*)(rb + GUARD + 16 * t);
    #pragma unroll
    for (int m4 = 0; m4 < 4; ++m4)
        o4[m4] = make_float4(acc[4*m4]*SC, acc[4*m4+1]*SC, acc[4*m4+2]*SC, acc[4*m4+3]*SC);
}

__global__ __launch_bounds__(256, 4) void k_bproj_sc(const float* __restrict__ ws,
                                                     const float* __restrict__ xaf,
                                                     float* __restrict__ out) {
    const float2* cst2 = (const float2*)(ws + OFF_CST2);
    int t = threadIdx.x;
    int tx = t & 15, ty = t >> 4;
    int bx = blockIdx.x, by = blockIdx.y, b = blockIdx.z;
    int xg = bx * 16 + tx, yg = by * 16 + ty;
    const float DEL = (float)(2.0 / 1023.0);
    float ux = __fadd_rn(__fmul_rn((float)xg, DEL), -1.0f);
    float uy = __fadd_rn(__fmul_rn((float)yg, DEL), -1.0f);

    float cx0 = __fadd_rn(__fmul_rn((float)(bx*16),      DEL), -1.0f);
    float cx1 = __fadd_rn(__fmul_rn((float)(bx*16 + 15), DEL), -1.0f);
    float cy0 = __fadd_rn(__fmul_rn((float)(by*16),      DEL), -1.0f);
    float cy1 = __fadd_rn(__fmul_rn((float)(by*16 + 15), DEL), -1.0f);
    float minax = (cx0 <= 0.f && cx1 >= 0.f) ? 0.f : fminf(fabsf(cx0), fabsf(cx1));
    float minay = (cy0 <= 0.f && cy1 >= 0.f) ? 0.f : fminf(fabsf(cy0), fabsf(cy1));
    float rmin2 = minax * minax + minay * minay;

    size_t oidx = ((size_t)b << 20) + ((size_t)yg << 10) + (size_t)xg;
    if (rmin2 > 1.000001f) { out[oidx] = 0.f; return; }

    const float* row = xaf + (size_t)b * (AA * RS);
    const float BIAS = 511.5f + (float)GUARD;
    float nuy = -uy;
    float acc = 0.f;

    #pragma unroll 4
    for (int a = 0; a < AA; ++a) {
        float2 cs = cst2[a];
        float iy = fmaf(ux, cs.x, fmaf(nuy, cs.y, BIAS));
        int j = (int)iy;
        float fy = fractf_(iy);
        float v0 = row[j];
        float v1 = row[j + 1];
        acc = fmaf(fy, v1 - v0, acc + v0);
        row += RS;
    }

    float r2 = __fadd_rn(__fmul_rn(ux, ux), __fmul_rn(uy, uy));
    out[oidx] = (r2 <= 1.0f) ? acc : 0.f;
}

extern "C" void kernel_launch(void* const* d_in, const int* in_sizes, int n_in,
                              void* d_out, int out_size, void* d_ws, size_t ws_size,
                              hipStream_t stream) {
    const float* x = (const float*)d_in[0];
    float* out = (float*)d_out;
    float* ws = (float*)d_ws;
    float* cg  = ws + OFF_CG;

    hipLaunchKernelGGL(k_tables, dim3(1), dim3(512), 0, stream, ws);

    size_t need_pair = (size_t)OFF_DATA * 4 + (size_t)NCOL * RSP * sizeof(float2);
    if (ws_size >= need_pair) {
        float2* pair = (float2*)(ws + OFF_DATA);
        hipLaunchKernelGGL(k_filter_pair, dim3(NCOL), dim3(64), 0, stream, x, cg, pair);
        hipLaunchKernelGGL(k_bproj_lds, dim3(16384), dim3(256), 0, stream, ws, pair, out);
    } else {
        float* xaf = ws + OFF_DATA;
        hipLaunchKernelGGL(k_filter_sc, dim3(NCOL), dim3(64), 0, stream, x, cg, xaf);
        hipLaunchKernelGGL(k_bproj_sc, dim3(64, 64, BB), dim3(256), 0, stream, ws, xaf, out);
    }
}

// Round 8
// 586.599 us; speedup vs baseline: 1.5344x; 1.5344x over previous
//
#include <hip/hip_runtime.h>
#include <math.h>

#define HH 1024
#define AA 180
#define BB 16
#define NCOL (BB*AA)          // 2880 (b,angle) columns
#define RSP 1028              // pair-row stride (float2 entries)
#define GUARD 48              // fallback path: zero guard floats each side
#define RS 1120               // fallback row stride
#define PI_D 3.14159265358979323846

#define GANG 45               // angles staged per group (180 = 4*45)
#define WIN 48                // window entries (float2) per angle

// ws float-offsets
#define OFF_CG   0            // 512 filter coeffs
#define OFF_CST  512          // float4[180]: (512c, 512s, D8=-8*DEL*512*s, 0)
#define OFF_CST2 1232         // float2[180]: (c,s) fallback table
#define OFF_DATA 1600         // pair rows (float2[NCOL*RSP]) or fallback xaf

__device__ __forceinline__ float fractf_(float x) {
#if __has_builtin(__builtin_amdgcn_fractf)
    return __builtin_amdgcn_fractf(x);   // v_fract_f32
#else
    return x - floorf(x);
#endif
}

// ---------------- tables ----------------
__global__ __launch_bounds__(512) void k_tables(float* __restrict__ ws) {
    int t = threadIdx.x;
    if (t < 512) {
        double d = 2.0 * t + 1.0;
        ws[OFF_CG + t] = (float)(-2.0 / (PI_D * PI_D * d * d));
    }
    if (t < AA) {
        float thf = (float)t * 0.017453292519943295f;  // fp32(pi/180)
        double th = (double)thf;
        double c = cos(th), s = sin(th);
        float4* cst4 = (float4*)(ws + OFF_CST);
        // D8 = d(iy)/d(k) for y-step of 8 pixels: -8*DEL*512*s = -(8192/1023)*s
        cst4[t] = make_float4((float)(512.0 * c), (float)(512.0 * s),
                              (float)(-(8192.0 / 1023.0) * s), 0.f);
        float2* cst2 = (float2*)(ws + OFF_CST2);
        cst2[t] = make_float2((float)(512.0 * c), (float)(512.0 * s));
    }
}

// ---------------- shared conv core (fused angle-interp + ramp filter) ----------------
// R8: coefficients staged into LDS (cgs). The previous global-uniform cg[511-it]
// compiled to per-chunk s_load; SMEM is out-of-order so its use forces
// lgkmcnt(0), draining the in-flight Lw/Rw ds_read prefetches every 8 iters
// (same mechanism as the R0->R1 bproj fix). LDS broadcast reads are in-order ->
// fine-grained lgkmcnt(N), ring buffer stays in flight. Values identical.
__device__ __forceinline__ void filter_core(const float* __restrict__ x,
                                            const float* __restrict__ cg,
                                            float* xsp, float* cgs,
                                            int t, int col,
                                            float acc[16]) {
    int b = col / AA, a = col - b * AA;

    // stage 512 coeffs -> LDS (2 float4/thread), covered by first barrier
    {
        const float4* cg4 = (const float4*)cg;
        float4* cgs4 = (float4*)cgs;
        cgs4[t]      = cg4[t];
        cgs4[t + 64] = cg4[t + 64];
    }

    float4* z4 = (float4*)xsp;
    #pragma unroll
    for (int i = t; i < 816; i += 64) z4[i] = make_float4(0.f, 0.f, 0.f, 0.f);
    __syncthreads();

    float ixf = (float)a * (float)(180.0/179.0) - 0.5f;
    float fl = floorf(ixf);
    int i0 = (int)fl;
    float fx = ixf - fl;
    float w0 = (i0 >= 0)      ? (1.0f - fx) : 0.0f;
    float w1 = (i0 + 1 < AA)  ? fx          : 0.0f;
    int c0 = max(i0, 0);
    int c1 = min(i0 + 1, AA - 1);
    const float* xb = x + (size_t)b * HH * AA;
    for (int i = t; i < HH; i += 64) {
        float v = w0 * xb[i * AA + c0] + w1 * xb[i * AA + c1];
        int q = 1024 + i;
        xsp[q + (q >> 4)] = v;         // lane stride 17 -> conflict-free
    }
    __syncthreads();

    int pp = 17 * t;
    float Lw[16], Rw[16];
    #pragma unroll
    for (int m = 0; m < 16; ++m) {
        int f = 1024 + m;
        acc[m] = 0.5f * xsp[pp + f + (f >> 4)];
    }
    #pragma unroll
    for (int m = 0; m < 16; ++m) {
        int f = 1 + m;
        Lw[(m + 1) & 15] = xsp[pp + f + (f >> 4)];
        int g = 2047 + m;
        Rw[(m - 1) & 15] = xsp[pp + g + (g >> 4)];
    }

    for (int it0 = 0; it0 < 512; it0 += 8) {
        #pragma unroll
        for (int u = 0; u < 8; ++u) {
            int it = it0 + u;
            float cv = cgs[511 - it];      // uniform LDS broadcast (in-order)
            #pragma unroll
            for (int m = 0; m < 16; ++m) {
                acc[m] = fmaf(cv, Lw[(m + 2*u + 1) & 15] + Rw[(m - 2*u - 1) & 15], acc[m]);
            }
            int fL  = 2*it + 17;
            Lw[(2*u + 1) & 15] = xsp[pp + fL  + (fL  >> 4)];
            int fL2 = 2*it + 18;
            Lw[(2*u + 2) & 15] = xsp[pp + fL2 + (fL2 >> 4)];
            int fR  = 2045 - 2*it;
            Rw[(13 - 2*u) & 15] = xsp[pp + fR  + (fR  >> 4)];
            int fR2 = 2046 - 2*it;
            Rw[(14 - 2*u) & 15] = xsp[pp + fR2 + (fR2 >> 4)];
        }
    }
}

// ---------------- pair-output filter (SLOPE layout) ----------------
// pair[s] = (y[s-2], y[s-1]-y[s-2]) * SC, zero outside; valid s in [0,1026].
__global__ __launch_bounds__(64) void k_filter_pair(const float* __restrict__ x,
                                                    const float* __restrict__ cg,
                                                    float2* __restrict__ pair) {
    __shared__ float xsp[3264];
    __shared__ float cgs[512];
    int t = threadIdx.x;
    int col = blockIdx.x;
    float acc[16];
    filter_core(x, cg, xsp, cgs, t, col, acc);

    const float SC = (float)(PI_D / 360.0);
    float yv[16];
    #pragma unroll
    for (int m = 0; m < 16; ++m) yv[m] = acc[m] * SC;
    float ynext = __shfl_down(yv[0], 1);
    if (t == 63) ynext = 0.f;

    float2* rowp = pair + (size_t)col * RSP;
    int s0 = 16 * t + 2;
    #pragma unroll
    for (int m = 0; m < 15; ++m) rowp[s0 + m] = make_float2(yv[m], yv[m + 1] - yv[m]);
    rowp[s0 + 15] = make_float2(yv[15], ynext - yv[15]);
    if (t == 0) {
        rowp[0] = make_float2(0.f, 0.f);
        rowp[1] = make_float2(0.f, yv[0]);     // (v=0, dv=y0-0)
    }
    if (t == 63) rowp[1026] = make_float2(0.f, 0.f);
}

// ---------------- LDS-staged backprojection (R1-proven, 482us) ----------------
// DS-issue-bound at ~96% of structural floor (ledger: 965k gather + 150k angf4
// + 50k staging ~= 1.165M cyc/CU ~= measured). Proven-dead alternatives:
// readlane consts (660), s_load chunks (513/519), global d3 gather (749),
// paired ds_read2 gathers (818, 100M bank conflicts). Do not revisit.
__global__ __launch_bounds__(256, 4) void k_bproj_lds(const float* __restrict__ ws,
                                                      const float2* __restrict__ pair,
                                                      float* __restrict__ out) {
    __shared__ float4 winbuf[GANG * (WIN/2)];   // 17280 B, 16B-aligned
    __shared__ float4 angf4[GANG];              // (512c, 512s, D8, bf)
    __shared__ int    baseL[GANG];

    const float4* cst = (const float4*)(ws + OFF_CST);
    int t = threadIdx.x;
    int n = blockIdx.x;
    // XCD-batch swizzle: blocks ≡ i (mod 8) handle batches {i, i+8} -> per-XCD
    // pair working set ~3 MB -> L2-resident.
    int b    = (n & 7) + 8 * ((n >> 3) & 1);
    int tile = n >> 4;                  // [0,1024)
    int bx = tile & 31;                 // x-tile (32 px)
    int by = tile >> 5;                 // y-tile (32 px)
    int tx = t & 31;
    int ty = t >> 5;                    // [0,8)
    int xg = bx * 32 + tx;
    int y0 = by * 32;
    int yg = y0 + ty;                   // pixel k at yg + 8k

    const float DEL = (float)(2.0 / 1023.0);
    // bit-exact jnp.linspace replication (mul then add, no contraction)
    float ux  = __fadd_rn(__fmul_rn((float)xg, DEL), -1.0f);
    float uy  = __fadd_rn(__fmul_rn((float)yg, DEL), -1.0f);
    float nuy = -uy;

    // tile-uniform corner coords
    float cxl = __fadd_rn(__fmul_rn((float)(bx*32),      DEL), -1.0f);
    float cxh = __fadd_rn(__fmul_rn((float)(bx*32 + 31), DEL), -1.0f);
    float cyl = __fadd_rn(__fmul_rn((float)(y0),         DEL), -1.0f);
    float cyh = __fadd_rn(__fmul_rn((float)(y0 + 31),    DEL), -1.0f);

    float minax = (cxl <= 0.f && cxh >= 0.f) ? 0.f : fminf(fabsf(cxl), fabsf(cxh));
    float minay = (cyl <= 0.f && cyh >= 0.f) ? 0.f : fminf(fabsf(cyl), fabsf(cyh));
    float rmin2 = minax * minax + minay * minay;
    float maxax = fmaxf(fabsf(cxl), fabsf(cxh));
    float maxay = fmaxf(fabsf(cyl), fabsf(cyh));
    float rmax2 = maxax * maxax + maxay * maxay;

    size_t o0 = ((size_t)b << 20) + ((size_t)yg << 10) + (size_t)xg;
    float* p0 = out + o0;

    if (rmin2 > 1.000001f) {            // tile fully outside: zeros, no barriers hit
        p0[0] = 0.f; p0[8 << 10] = 0.f; p0[16 << 10] = 0.f; p0[24 << 10] = 0.f;
        return;
    }

    bool interior = (rmax2 <= 0.9999f);
    const float2* slab = pair + (size_t)b * (AA * RSP);
    const float2* win = (const float2*)winbuf;
    float a0 = 0.f, a1 = 0.f, a2 = 0.f, a3 = 0.f;
    float nyl = -cyl, nyh = -cyh;

    for (int g0 = 0; g0 < AA; g0 += GANG) {
        // --- per-angle window bases + constants (tile-uniform) ---
        if (t < GANG) {
            float4 cs = cst[g0 + t];    // vector load (t varies)
            float mpx = fminf(cxl * cs.x, cxh * cs.x);
            float mpy = fminf(nyl * cs.y, nyh * cs.y);
            float minP = mpx + mpy + 513.5f;
            int base = (int)floorf(minP) - 1;
            base = min(max(base, 0), 1027 - WIN);
            base &= ~1;                 // 16B-align window for float4 staging
            baseL[t] = base;
            angf4[t] = make_float4(cs.x, cs.y, cs.z, 513.5f - (float)base);
        }
        __syncthreads();

        // --- coalesced staging: 45 angles x 24 float4 (48 float2) ---
        for (int idx = t; idx < GANG * (WIN/2); idx += 256) {
            int al = idx / (WIN/2);
            int w  = idx - (WIN/2) * al;
            const float4* rp4 = (const float4*)(slab + (size_t)(g0 + al) * RSP + baseL[al]);
            winbuf[idx] = rp4[w];
        }
        __syncthreads();

        // --- compute 45 angles from LDS (DS-only loop) ---
        if (interior) {
            #pragma unroll 5
            for (int g = 0; g < GANG; ++g) {
                float4 cb = angf4[g];           // one ds_read_b128 broadcast
                float P0 = fmaf(ux, cb.x, fmaf(nuy, cb.y, cb.w));
                float P1 = P0 + cb.z;
                float P2 = fmaf(2.0f, cb.z, P0);
                float P3 = P2 + cb.z;
                int j0 = (int)P0, j1 = (int)P1, j2 = (int)P2, j3 = (int)P3;
                const float2* wg = win + g * WIN;
                float2 d0 = wg[j0];
                float2 d1 = wg[j1];
                float2 d2 = wg[j2];
                float2 d3 = wg[j3];
                float f0 = fractf_(P0), f1 = fractf_(P1), f2v = fractf_(P2), f3 = fractf_(P3);
                a0 = fmaf(f0, d0.y, a0 + d0.x);
                a1 = fmaf(f1, d1.y, a1 + d1.x);
                a2 = fmaf(f2v, d2.y, a2 + d2.x);
                a3 = fmaf(f3, d3.y, a3 + d3.x);
            }
        } else {
            #pragma unroll 5
            for (int g = 0; g < GANG; ++g) {
                float4 cb = angf4[g];
                float P0 = fmaf(ux, cb.x, fmaf(nuy, cb.y, cb.w));
                float P1 = P0 + cb.z;
                float P2 = fmaf(2.0f, cb.z, P0);
                float P3 = P2 + cb.z;
                int j0 = (int)P0, j1 = (int)P1, j2 = (int)P2, j3 = (int)P3;
                j0 = min(max(j0, 0), WIN - 1); j1 = min(max(j1, 0), WIN - 1);
                j2 = min(max(j2, 0), WIN - 1); j3 = min(max(j3, 0), WIN - 1);
                const float2* wg = win + g * WIN;
                float2 d0 = wg[j0];
                float2 d1 = wg[j1];
                float2 d2 = wg[j2];
                float2 d3 = wg[j3];
                float f0 = fractf_(P0), f1 = fractf_(P1), f2v = fractf_(P2), f3 = fractf_(P3);
                a0 = fmaf(f0, d0.y, a0 + d0.x);
                a1 = fmaf(f1, d1.y, a1 + d1.x);
                a2 = fmaf(f2v, d2.y, a2 + d2.x);
                a3 = fmaf(f3, d3.y, a3 + d3.x);
            }
        }
        __syncthreads();   // protect baseL/angf4/win before next group
    }

    if (interior) {
        p0[0] = a0; p0[8 << 10] = a1; p0[16 << 10] = a2; p0[24 << 10] = a3;
    } else {
        // bit-exact circle mask per pixel (in-circle px had exact j/fract; out px masked)
        float uy1 = __fadd_rn(__fmul_rn((float)(yg + 8),  DEL), -1.0f);
        float uy2 = __fadd_rn(__fmul_rn((float)(yg + 16), DEL), -1.0f);
        float uy3 = __fadd_rn(__fmul_rn((float)(yg + 24), DEL), -1.0f);
        float xx = __fmul_rn(ux, ux);
        float r20 = __fadd_rn(xx, __fmul_rn(uy,  uy));
        float r21 = __fadd_rn(xx, __fmul_rn(uy1, uy1));
        float r22 = __fadd_rn(xx, __fmul_rn(uy2, uy2));
        float r23 = __fadd_rn(xx, __fmul_rn(uy3, uy3));
        p0[0]        = (r20 <= 1.0f) ? a0 : 0.f;
        p0[8 << 10]  = (r21 <= 1.0f) ? a1 : 0.f;
        p0[16 << 10] = (r22 <= 1.0f) ? a2 : 0.f;
        p0[24 << 10] = (r23 <= 1.0f) ? a3 : 0.f;
    }
}

// ================= fallback path (proven) — used if ws too small ==========
__global__ __launch_bounds__(64) void k_filter_sc(const float* __restrict__ x,
                                                  const float* __restrict__ cg,
                                                  float* __restrict__ xaf) {
    __shared__ float xsp[3264];
    __shared__ float cgs[512];
    int t = threadIdx.x;
    int col = blockIdx.x;
    float acc[16];
    filter_core(x, cg, xsp, cgs, t, col, acc);

    const float SC = (float)(PI_D / 360.0);
    float* rb = xaf + (size_t)col * RS;
    if (t < 12)            ((float4*)rb)[t]              = make_float4(0.f,0.f,0.f,0.f);
    else if (t < 24)       ((float4*)rb)[268 + (t - 12)] = make_float4(0.f,0.f,0.f,0.f);
    float4* o4 = (float4*)(rb + GUARD + 16 * t);
    #pragma unroll
    for (int m4 = 0; m4 < 4; ++m4)
        o4[m4] = make_float4(acc[4*m4]*SC, acc[4*m4+1]*SC, acc[4*m4+2]*SC, acc[4*m4+3]*SC);
}

__global__ __launch_bounds__(256, 4) void k_bproj_sc(const float* __restrict__ ws,
                                                     const float* __restrict__ xaf,
                                                     float* __restrict__ out) {
    const float2* cst2 = (const float2*)(ws + OFF_CST2);
    int t = threadIdx.x;
    int tx = t & 15, ty = t >> 4;
    int bx = blockIdx.x, by = blockIdx.y, b = blockIdx.z;
    int xg = bx * 16 + tx, yg = by * 16 + ty;
    const float DEL = (float)(2.0 / 1023.0);
    float ux = __fadd_rn(__fmul_rn((float)xg, DEL), -1.0f);
    float uy = __fadd_rn(__fmul_rn((float)yg, DEL), -1.0f);

    float cx0 = __fadd_rn(__fmul_rn((float)(bx*16),      DEL), -1.0f);
    float cx1 = __fadd_rn(__fmul_rn((float)(bx*16 + 15), DEL), -1.0f);
    float cy0 = __fadd_rn(__fmul_rn((float)(by*16),      DEL), -1.0f);
    float cy1 = __fadd_rn(__fmul_rn((float)(by*16 + 15), DEL), -1.0f);
    float minax = (cx0 <= 0.f && cx1 >= 0.f) ? 0.f : fminf(fabsf(cx0), fabsf(cx1));
    float minay = (cy0 <= 0.f && cy1 >= 0.f) ? 0.f : fminf(fabsf(cy0), fabsf(cy1));
    float rmin2 = minax * minax + minay * minay;

    size_t oidx = ((size_t)b << 20) + ((size_t)yg << 10) + (size_t)xg;
    if (rmin2 > 1.000001f) { out[oidx] = 0.f; return; }

    const float* row = xaf + (size_t)b * (AA * RS);
    const float BIAS = 511.5f + (float)GUARD;
    float nuy = -uy;
    float acc = 0.f;

    #pragma unroll 4
    for (int a = 0; a < AA; ++a) {
        float2 cs = cst2[a];
        float iy = fmaf(ux, cs.x, fmaf(nuy, cs.y, BIAS));
        int j = (int)iy;
        float fy = fractf_(iy);
        float v0 = row[j];
        float v1 = row[j + 1];
        acc = fmaf(fy, v1 - v0, acc + v0);
        row += RS;
    }

    float r2 = __fadd_rn(__fmul_rn(ux, ux), __fmul_rn(uy, uy));
    out[oidx] = (r2 <= 1.0f) ? acc : 0.f;
}

extern "C" void kernel_launch(void* const* d_in, const int* in_sizes, int n_in,
                              void* d_out, int out_size, void* d_ws, size_t ws_size,
                              hipStream_t stream) {
    const float* x = (const float*)d_in[0];
    float* out = (float*)d_out;
    float* ws = (float*)d_ws;
    float* cg  = ws + OFF_CG;

    hipLaunchKernelGGL(k_tables, dim3(1), dim3(512), 0, stream, ws);

    size_t need_pair = (size_t)OFF_DATA * 4 + (size_t)NCOL * RSP * sizeof(float2);
    if (ws_size >= need_pair) {
        float2* pair = (float2*)(ws + OFF_DATA);
        hipLaunchKernelGGL(k_filter_pair, dim3(NCOL), dim3(64), 0, stream, x, cg, pair);
        hipLaunchKernelGGL(k_bproj_lds, dim3(16384), dim3(256), 0, stream, ws, pair, out);
    } else {
        float* xaf = ws + OFF_DATA;
        hipLaunchKernelGGL(k_filter_sc, dim3(NCOL), dim3(64), 0, stream, x, cg, xaf);
        hipLaunchKernelGGL(k_bproj_sc, dim3(64, 64, BB), dim3(256), 0, stream, ws, xaf, out);
    }
}

// Round 9
// 570.567 us; speedup vs baseline: 1.5775x; 1.0281x over previous
//
#include <hip/hip_runtime.h>
#include <math.h>

#define HH 1024
#define AA 180
#define BB 16
#define NCOL (BB*AA)          // 2880 (b,angle) columns
#define RSP 1028              // pair-row stride (float2 entries)
#define GUARD 48              // fallback path: zero guard floats each side
#define RS 1120               // fallback row stride
#define PI_D 3.14159265358979323846

#define GANG 45               // angles staged per group (180 = 4*45)
#define WIN 48                // window entries (float2) per angle

// ws float-offsets
#define OFF_CG   0            // 512 filter coeffs
#define OFF_CST  512          // float4[180]: (512c, 512s, D8=-8*DEL*512*s, 0)
#define OFF_CST2 1232         // float2[180]: (c,s) fallback table
#define OFF_DATA 1600         // pair rows (float2[NCOL*RSP]) or fallback xaf

__device__ __forceinline__ float fractf_(float x) {
#if __has_builtin(__builtin_amdgcn_fractf)
    return __builtin_amdgcn_fractf(x);   // v_fract_f32
#else
    return x - floorf(x);
#endif
}

// ---------------- tables ----------------
__global__ __launch_bounds__(512) void k_tables(float* __restrict__ ws) {
    int t = threadIdx.x;
    if (t < 512) {
        double d = 2.0 * t + 1.0;
        ws[OFF_CG + t] = (float)(-2.0 / (PI_D * PI_D * d * d));
    }
    if (t < AA) {
        float thf = (float)t * 0.017453292519943295f;  // fp32(pi/180)
        double th = (double)thf;
        double c = cos(th), s = sin(th);
        float4* cst4 = (float4*)(ws + OFF_CST);
        // D8 = d(iy)/d(k) for y-step of 8 pixels: -8*DEL*512*s = -(8192/1023)*s
        cst4[t] = make_float4((float)(512.0 * c), (float)(512.0 * s),
                              (float)(-(8192.0 / 1023.0) * s), 0.f);
        float2* cst2 = (float2*)(ws + OFF_CST2);
        cst2[t] = make_float2((float)(512.0 * c), (float)(512.0 * s));
    }
}

// ---------------- 2-wave split conv core (R9) ----------------
// 128 threads/block, one column. The filter was GRID-parallelism-bound:
// 2880 1-wave blocks = 2.8 waves/SIMD -> ds_read->fma chains can't overlap.
// Split taps across 2 waves sharing xsp (LDS/block unchanged -> 10 blocks/CU
// now = 20 waves/CU = 5/SIMD): wave0 = 0.5*center + taps 0..255, wave1 = taps
// 256..511; merge via the unused zero-guard region of xsp (m*64+lane layout,
// conflict-free). Per-tap op order unchanged; ONE reassociation at the merge
// (err ~1e-6 << 4.1e-3 threshold).
__device__ __forceinline__ void filter_half(const float* xsp, const float* cgs,
                                            int lane, int w, float acc[16]) {
    int pp = 17 * lane;
    float Lw[16], Rw[16];
    int itBase = 256 * w;
    #pragma unroll
    for (int m = 0; m < 16; ++m) {
        int f = 1024 + m;
        acc[m] = w ? 0.f : 0.5f * xsp[pp + f + (f >> 4)];
    }
    #pragma unroll
    for (int m = 0; m < 16; ++m) {
        int f = 512 * w + 1 + m;            // w=0: 1+m (R1 init); w=1: ring state at it=256
        Lw[(m + 1) & 15] = xsp[pp + f + (f >> 4)];
        int g = 2047 - 512 * w + m;         // w=0: 2047+m; w=1: 1535+m
        Rw[(m - 1) & 15] = xsp[pp + g + (g >> 4)];
    }

    for (int it0 = itBase; it0 < itBase + 256; it0 += 8) {
        #pragma unroll
        for (int u = 0; u < 8; ++u) {
            int it = it0 + u;
            float cv = cgs[511 - it];
            #pragma unroll
            for (int m = 0; m < 16; ++m) {
                acc[m] = fmaf(cv, Lw[(m + 2*u + 1) & 15] + Rw[(m - 2*u - 1) & 15], acc[m]);
            }
            int fL  = 2*it + 17;
            Lw[(2*u + 1) & 15] = xsp[pp + fL  + (fL  >> 4)];
            int fL2 = 2*it + 18;
            Lw[(2*u + 2) & 15] = xsp[pp + fL2 + (fL2 >> 4)];
            int fR  = 2045 - 2*it;
            Rw[(13 - 2*u) & 15] = xsp[pp + fR  + (fR  >> 4)];
            int fR2 = 2046 - 2*it;
            Rw[(14 - 2*u) & 15] = xsp[pp + fR2 + (fR2 >> 4)];
        }
    }
}

// ---------------- pair-output filter (SLOPE layout, 2-wave) ----------------
// pair[s] = (y[s-2], y[s-1]-y[s-2]) * SC, zero outside; valid s in [0,1026].
__global__ __launch_bounds__(128) void k_filter_pair(const float* __restrict__ x,
                                                     const float* __restrict__ cg,
                                                     float2* __restrict__ pair) {
    __shared__ float xsp[3264];
    __shared__ float cgs[512];
    int t = threadIdx.x;
    int lane = t & 63;
    int w = t >> 6;
    int col = blockIdx.x;
    int b = col / AA, a = col - b * AA;

    // stage 512 coeffs (128 x float4) + zero-init xsp
    ((float4*)cgs)[t] = ((const float4*)cg)[t];
    float4* z4 = (float4*)xsp;
    #pragma unroll
    for (int i = t; i < 816; i += 128) z4[i] = make_float4(0.f, 0.f, 0.f, 0.f);
    __syncthreads();

    float ixf = (float)a * (float)(180.0/179.0) - 0.5f;
    float fl = floorf(ixf);
    int i0 = (int)fl;
    float fx = ixf - fl;
    float w0 = (i0 >= 0)      ? (1.0f - fx) : 0.0f;
    float w1 = (i0 + 1 < AA)  ? fx          : 0.0f;
    int c0 = max(i0, 0);
    int c1 = min(i0 + 1, AA - 1);
    const float* xb = x + (size_t)b * HH * AA;
    for (int i = t; i < HH; i += 128) {
        float v = w0 * xb[i * AA + c0] + w1 * xb[i * AA + c1];
        int q = 1024 + i;
        xsp[q + (q >> 4)] = v;         // lane stride 17 -> conflict-free
    }
    __syncthreads();

    float acc[16];
    filter_half(xsp, cgs, lane, w, acc);

    // merge: wave1 -> zero-guard region of xsp (padded reads end at 2190 < 2200)
    float* accs = xsp + 2200;          // 1024 floats, fits (2200+1023 = 3223 < 3264)
    if (w == 1) {
        #pragma unroll
        for (int m = 0; m < 16; ++m) accs[m * 64 + lane] = acc[m];  // conflict-free
    }
    __syncthreads();
    if (w == 1) return;
    #pragma unroll
    for (int m = 0; m < 16; ++m) acc[m] += accs[m * 64 + lane];

    const float SC = (float)(PI_D / 360.0);
    float yv[16];
    #pragma unroll
    for (int m = 0; m < 16; ++m) yv[m] = acc[m] * SC;
    float ynext = __shfl_down(yv[0], 1);
    if (lane == 63) ynext = 0.f;

    float2* rowp = pair + (size_t)col * RSP;
    int s0 = 16 * lane + 2;
    #pragma unroll
    for (int m = 0; m < 15; ++m) rowp[s0 + m] = make_float2(yv[m], yv[m + 1] - yv[m]);
    rowp[s0 + 15] = make_float2(yv[15], ynext - yv[15]);
    if (lane == 0) {
        rowp[0] = make_float2(0.f, 0.f);
        rowp[1] = make_float2(0.f, yv[0]);     // (v=0, dv=y0-0)
    }
    if (lane == 63) rowp[1026] = make_float2(0.f, 0.f);
}

// ---------------- LDS-staged backprojection (R1-proven, 482us — DO NOT TOUCH) ----------------
// DS-issue-bound at ~96% of structural floor (ledger: 965k gather + 150k angf4
// + 50k staging ~= 1.165M cyc/CU ~= measured 1.157M). Proven-dead alternatives:
// readlane consts (660), s_load chunks (513/519), global d3 gather (749),
// paired ds_read2 gathers (818, 100M bank conflicts). Gathers run at ~LDS
// byte-BW (65.7 of ~85 B/cyc incl. broadcasts/staging). Do not revisit.
__global__ __launch_bounds__(256, 4) void k_bproj_lds(const float* __restrict__ ws,
                                                      const float2* __restrict__ pair,
                                                      float* __restrict__ out) {
    __shared__ float4 winbuf[GANG * (WIN/2)];   // 17280 B, 16B-aligned
    __shared__ float4 angf4[GANG];              // (512c, 512s, D8, bf)
    __shared__ int    baseL[GANG];

    const float4* cst = (const float4*)(ws + OFF_CST);
    int t = threadIdx.x;
    int n = blockIdx.x;
    // XCD-batch swizzle: blocks ≡ i (mod 8) handle batches {i, i+8} -> per-XCD
    // pair working set ~3 MB -> L2-resident.
    int b    = (n & 7) + 8 * ((n >> 3) & 1);
    int tile = n >> 4;                  // [0,1024)
    int bx = tile & 31;                 // x-tile (32 px)
    int by = tile >> 5;                 // y-tile (32 px)
    int tx = t & 31;
    int ty = t >> 5;                    // [0,8)
    int xg = bx * 32 + tx;
    int y0 = by * 32;
    int yg = y0 + ty;                   // pixel k at yg + 8k

    const float DEL = (float)(2.0 / 1023.0);
    // bit-exact jnp.linspace replication (mul then add, no contraction)
    float ux  = __fadd_rn(__fmul_rn((float)xg, DEL), -1.0f);
    float uy  = __fadd_rn(__fmul_rn((float)yg, DEL), -1.0f);
    float nuy = -uy;

    // tile-uniform corner coords
    float cxl = __fadd_rn(__fmul_rn((float)(bx*32),      DEL), -1.0f);
    float cxh = __fadd_rn(__fmul_rn((float)(bx*32 + 31), DEL), -1.0f);
    float cyl = __fadd_rn(__fmul_rn((float)(y0),         DEL), -1.0f);
    float cyh = __fadd_rn(__fmul_rn((float)(y0 + 31),    DEL), -1.0f);

    float minax = (cxl <= 0.f && cxh >= 0.f) ? 0.f : fminf(fabsf(cxl), fabsf(cxh));
    float minay = (cyl <= 0.f && cyh >= 0.f) ? 0.f : fminf(fabsf(cyl), fabsf(cyh));
    float rmin2 = minax * minax + minay * minay;
    float maxax = fmaxf(fabsf(cxl), fabsf(cxh));
    float maxay = fmaxf(fabsf(cyl), fabsf(cyh));
    float rmax2 = maxax * maxax + maxay * maxay;

    size_t o0 = ((size_t)b << 20) + ((size_t)yg << 10) + (size_t)xg;
    float* p0 = out + o0;

    if (rmin2 > 1.000001f) {            // tile fully outside: zeros, no barriers hit
        p0[0] = 0.f; p0[8 << 10] = 0.f; p0[16 << 10] = 0.f; p0[24 << 10] = 0.f;
        return;
    }

    bool interior = (rmax2 <= 0.9999f);
    const float2* slab = pair + (size_t)b * (AA * RSP);
    const float2* win = (const float2*)winbuf;
    float a0 = 0.f, a1 = 0.f, a2 = 0.f, a3 = 0.f;
    float nyl = -cyl, nyh = -cyh;

    for (int g0 = 0; g0 < AA; g0 += GANG) {
        // --- per-angle window bases + constants (tile-uniform) ---
        if (t < GANG) {
            float4 cs = cst[g0 + t];    // vector load (t varies)
            float mpx = fminf(cxl * cs.x, cxh * cs.x);
            float mpy = fminf(nyl * cs.y, nyh * cs.y);
            float minP = mpx + mpy + 513.5f;
            int base = (int)floorf(minP) - 1;
            base = min(max(base, 0), 1027 - WIN);
            base &= ~1;                 // 16B-align window for float4 staging
            baseL[t] = base;
            angf4[t] = make_float4(cs.x, cs.y, cs.z, 513.5f - (float)base);
        }
        __syncthreads();

        // --- coalesced staging: 45 angles x 24 float4 (48 float2) ---
        for (int idx = t; idx < GANG * (WIN/2); idx += 256) {
            int al = idx / (WIN/2);
            int w  = idx - (WIN/2) * al;
            const float4* rp4 = (const float4*)(slab + (size_t)(g0 + al) * RSP + baseL[al]);
            winbuf[idx] = rp4[w];
        }
        __syncthreads();

        // --- compute 45 angles from LDS (DS-only loop) ---
        if (interior) {
            #pragma unroll 5
            for (int g = 0; g < GANG; ++g) {
                float4 cb = angf4[g];           // one ds_read_b128 broadcast
                float P0 = fmaf(ux, cb.x, fmaf(nuy, cb.y, cb.w));
                float P1 = P0 + cb.z;
                float P2 = fmaf(2.0f, cb.z, P0);
                float P3 = P2 + cb.z;
                int j0 = (int)P0, j1 = (int)P1, j2 = (int)P2, j3 = (int)P3;
                const float2* wg = win + g * WIN;
                float2 d0 = wg[j0];
                float2 d1 = wg[j1];
                float2 d2 = wg[j2];
                float2 d3 = wg[j3];
                float f0 = fractf_(P0), f1 = fractf_(P1), f2v = fractf_(P2), f3 = fractf_(P3);
                a0 = fmaf(f0, d0.y, a0 + d0.x);
                a1 = fmaf(f1, d1.y, a1 + d1.x);
                a2 = fmaf(f2v, d2.y, a2 + d2.x);
                a3 = fmaf(f3, d3.y, a3 + d3.x);
            }
        } else {
            #pragma unroll 5
            for (int g = 0; g < GANG; ++g) {
                float4 cb = angf4[g];
                float P0 = fmaf(ux, cb.x, fmaf(nuy, cb.y, cb.w));
                float P1 = P0 + cb.z;
                float P2 = fmaf(2.0f, cb.z, P0);
                float P3 = P2 + cb.z;
                int j0 = (int)P0, j1 = (int)P1, j2 = (int)P2, j3 = (int)P3;
                j0 = min(max(j0, 0), WIN - 1); j1 = min(max(j1, 0), WIN - 1);
                j2 = min(max(j2, 0), WIN - 1); j3 = min(max(j3, 0), WIN - 1);
                const float2* wg = win + g * WIN;
                float2 d0 = wg[j0];
                float2 d1 = wg[j1];
                float2 d2 = wg[j2];
                float2 d3 = wg[j3];
                float f0 = fractf_(P0), f1 = fractf_(P1), f2v = fractf_(P2), f3 = fractf_(P3);
                a0 = fmaf(f0, d0.y, a0 + d0.x);
                a1 = fmaf(f1, d1.y, a1 + d1.x);
                a2 = fmaf(f2v, d2.y, a2 + d2.x);
                a3 = fmaf(f3, d3.y, a3 + d3.x);
            }
        }
        __syncthreads();   // protect baseL/angf4/win before next group
    }

    if (interior) {
        p0[0] = a0; p0[8 << 10] = a1; p0[16 << 10] = a2; p0[24 << 10] = a3;
    } else {
        // bit-exact circle mask per pixel (in-circle px had exact j/fract; out px masked)
        float uy1 = __fadd_rn(__fmul_rn((float)(yg + 8),  DEL), -1.0f);
        float uy2 = __fadd_rn(__fmul_rn((float)(yg + 16), DEL), -1.0f);
        float uy3 = __fadd_rn(__fmul_rn((float)(yg + 24), DEL), -1.0f);
        float xx = __fmul_rn(ux, ux);
        float r20 = __fadd_rn(xx, __fmul_rn(uy,  uy));
        float r21 = __fadd_rn(xx, __fmul_rn(uy1, uy1));
        float r22 = __fadd_rn(xx, __fmul_rn(uy2, uy2));
        float r23 = __fadd_rn(xx, __fmul_rn(uy3, uy3));
        p0[0]        = (r20 <= 1.0f) ? a0 : 0.f;
        p0[8 << 10]  = (r21 <= 1.0f) ? a1 : 0.f;
        p0[16 << 10] = (r22 <= 1.0f) ? a2 : 0.f;
        p0[24 << 10] = (r23 <= 1.0f) ? a3 : 0.f;
    }
}

// ================= fallback path (proven) — used if ws too small ==========
__device__ __forceinline__ void filter_core_sc(const float* __restrict__ x,
                                               const float* __restrict__ cg,
                                               float* xsp, int t, int col,
                                               float acc[16]) {
    int b = col / AA, a = col - b * AA;

    float4* z4 = (float4*)xsp;
    #pragma unroll
    for (int i = t; i < 816; i += 64) z4[i] = make_float4(0.f, 0.f, 0.f, 0.f);
    __syncthreads();

    float ixf = (float)a * (float)(180.0/179.0) - 0.5f;
    float fl = floorf(ixf);
    int i0 = (int)fl;
    float fx = ixf - fl;
    float w0 = (i0 >= 0)      ? (1.0f - fx) : 0.0f;
    float w1 = (i0 + 1 < AA)  ? fx          : 0.0f;
    int c0 = max(i0, 0);
    int c1 = min(i0 + 1, AA - 1);
    const float* xb = x + (size_t)b * HH * AA;
    for (int i = t; i < HH; i += 64) {
        float v = w0 * xb[i * AA + c0] + w1 * xb[i * AA + c1];
        int q = 1024 + i;
        xsp[q + (q >> 4)] = v;
    }
    __syncthreads();

    int pp = 17 * t;
    float Lw[16], Rw[16];
    #pragma unroll
    for (int m = 0; m < 16; ++m) {
        int f = 1024 + m;
        acc[m] = 0.5f * xsp[pp + f + (f >> 4)];
    }
    #pragma unroll
    for (int m = 0; m < 16; ++m) {
        int f = 1 + m;
        Lw[(m + 1) & 15] = xsp[pp + f + (f >> 4)];
        int g = 2047 + m;
        Rw[(m - 1) & 15] = xsp[pp + g + (g >> 4)];
    }

    for (int it0 = 0; it0 < 512; it0 += 8) {
        #pragma unroll
        for (int u = 0; u < 8; ++u) {
            int it = it0 + u;
            float cv = cg[511 - it];
            #pragma unroll
            for (int m = 0; m < 16; ++m) {
                acc[m] = fmaf(cv, Lw[(m + 2*u + 1) & 15] + Rw[(m - 2*u - 1) & 15], acc[m]);
            }
            int fL  = 2*it + 17;
            Lw[(2*u + 1) & 15] = xsp[pp + fL  + (fL  >> 4)];
            int fL2 = 2*it + 18;
            Lw[(2*u + 2) & 15] = xsp[pp + fL2 + (fL2 >> 4)];
            int fR  = 2045 - 2*it;
            Rw[(13 - 2*u) & 15] = xsp[pp + fR  + (fR  >> 4)];
            int fR2 = 2046 - 2*it;
            Rw[(14 - 2*u) & 15] = xsp[pp + fR2 + (fR2 >> 4)];
        }
    }
}

__global__ __launch_bounds__(64) void k_filter_sc(const float* __restrict__ x,
                                                  const float* __restrict__ cg,
                                                  float* __restrict__ xaf) {
    __shared__ float xsp[3264];
    int t = threadIdx.x;
    int col = blockIdx.x;
    float acc[16];
    filter_core_sc(x, cg, xsp, t, col, acc);

    const float SC = (float)(PI_D / 360.0);
    float* rb = xaf + (size_t)col * RS;
    if (t < 12)            ((float4*)rb)[t]              = make_float4(0.f,0.f,0.f,0.f);
    else if (t < 24)       ((float4*)rb)[268 + (t - 12)] = make_float4(0.f,0.f,0.f,0.f);
    float4* o4 = (float4*)(rb + GUARD + 16 * t);
    #pragma unroll
    for (int m4 = 0; m4 < 4; ++m4)
        o4[m4] = make_float4(acc[4*m4]*SC, acc[4*m4+1]*SC, acc[4*m4+2]*SC, acc[4*m4+3]*SC);
}

__global__ __launch_bounds__(256, 4) void k_bproj_sc(const float* __restrict__ ws,
                                                     const float* __restrict__ xaf,
                                                     float* __restrict__ out) {
    const float2* cst2 = (const float2*)(ws + OFF_CST2);
    int t = threadIdx.x;
    int tx = t & 15, ty = t >> 4;
    int bx = blockIdx.x, by = blockIdx.y, b = blockIdx.z;
    int xg = bx * 16 + tx, yg = by * 16 + ty;
    const float DEL = (float)(2.0 / 1023.0);
    float ux = __fadd_rn(__fmul_rn((float)xg, DEL), -1.0f);
    float uy = __fadd_rn(__fmul_rn((float)yg, DEL), -1.0f);

    float cx0 = __fadd_rn(__fmul_rn((float)(bx*16),      DEL), -1.0f);
    float cx1 = __fadd_rn(__fmul_rn((float)(bx*16 + 15), DEL), -1.0f);
    float cy0 = __fadd_rn(__fmul_rn((float)(by*16),      DEL), -1.0f);
    float cy1 = __fadd_rn(__fmul_rn((float)(by*16 + 15), DEL), -1.0f);
    float minax = (cx0 <= 0.f && cx1 >= 0.f) ? 0.f : fminf(fabsf(cx0), fabsf(cx1));
    float minay = (cy0 <= 0.f && cy1 >= 0.f) ? 0.f : fminf(fabsf(cy0), fabsf(cy1));
    float rmin2 = minax * minax + minay * minay;

    size_t oidx = ((size_t)b << 20) + ((size_t)yg << 10) + (size_t)xg;
    if (rmin2 > 1.000001f) { out[oidx] = 0.f; return; }

    const float* row = xaf + (size_t)b * (AA * RS);
    const float BIAS = 511.5f + (float)GUARD;
    float nuy = -uy;
    float acc = 0.f;

    #pragma unroll 4
    for (int a = 0; a < AA; ++a) {
        float2 cs = cst2[a];
        float iy = fmaf(ux, cs.x, fmaf(nuy, cs.y, BIAS));
        int j = (int)iy;
        float fy = fractf_(iy);
        float v0 = row[j];
        float v1 = row[j + 1];
        acc = fmaf(fy, v1 - v0, acc + v0);
        row += RS;
    }

    float r2 = __fadd_rn(__fmul_rn(ux, ux), __fmul_rn(uy, uy));
    out[oidx] = (r2 <= 1.0f) ? acc : 0.f;
}

extern "C" void kernel_launch(void* const* d_in, const int* in_sizes, int n_in,
                              void* d_out, int out_size, void* d_ws, size_t ws_size,
                              hipStream_t stream) {
    const float* x = (const float*)d_in[0];
    float* out = (float*)d_out;
    float* ws = (float*)d_ws;
    float* cg  = ws + OFF_CG;

    hipLaunchKernelGGL(k_tables, dim3(1), dim3(512), 0, stream, ws);

    size_t need_pair = (size_t)OFF_DATA * 4 + (size_t)NCOL * RSP * sizeof(float2);
    if (ws_size >= need_pair) {
        float2* pair = (float2*)(ws + OFF_DATA);
        hipLaunchKernelGGL(k_filter_pair, dim3(NCOL), dim3(128), 0, stream, x, cg, pair);
        hipLaunchKernelGGL(k_bproj_lds, dim3(16384), dim3(256), 0, stream, ws, pair, out);
    } else {
        float* xaf = ws + OFF_DATA;
        hipLaunchKernelGGL(k_filter_sc, dim3(NCOL), dim3(64), 0, stream, x, cg, xaf);
        hipLaunchKernelGGL(k_bproj_sc, dim3(64, 64, BB), dim3(256), 0, stream, ws, xaf, out);
    }
}